// Round 3
// baseline (256.614 us; speedup 1.0000x reference)
//
#include <hip/hip_runtime.h>

#define BB 8
#define HH 1024
#define WW 1280
#define HW (HH * WW)
#define EPSF 1e-7f

// 8-byte vector with 4-byte alignment: gfx950 supports unaligned global dwordx2.
typedef float f2u __attribute__((ext_vector_type(2), aligned(4)));

__device__ __forceinline__ float fast_rcp(float x) {
    float r = __builtin_amdgcn_rcpf(x);
    r = r * __builtin_fmaf(-x, r, 2.0f);   // one NR step -> ~1 ulp
    return r;
}

// Per-batch constant folding: 8 threads, negligible. Writes 8 floats per batch.
__global__ void precompute_consts(
    const float* __restrict__ srcK, const float* __restrict__ tgtK,
    const float* __restrict__ trans, float* __restrict__ cb)
{
    const int b = threadIdx.x;
    if (b >= BB) return;
    const float* sK = srcK + b * 16;
    const float* tK = tgtK + b * 16;
    const float* tv = trans + b * 3;

    const float fsx = sK[0], csx = sK[2];
    const float fsy = sK[5], csy = sK[6];
    const float ftx = tK[0], ctx = tK[2];
    const float fty = tK[5], cty = tK[6];
    const float t0 = tv[0], t1 = tv[1], t2 = tv[2];

    // Closed form (K last row = [0,0,1], R = I):
    //   px = (A00*x + A02 + C0*sd) / (1 + (t2+eps)*sd),  sd = scaled_disp = 1/depth
    //   sx = px*W/(W-1) - 0.5   (grid unnormalize folded into A/C)
    const float Sx = (float)WW / (float)(WW - 1);
    const float Sy = (float)HH / (float)(HH - 1);
    const float rfsx = 1.0f / fsx;
    const float rfsy = 1.0f / fsy;
    float* c = cb + b * 8;
    c[0] = ftx * rfsx * Sx;                                    // A00
    c[1] = __builtin_fmaf(-ftx * csx, rfsx, ctx) * Sx;         // A02
    c[2] = (ftx * t0 + ctx * t2) * Sx;                         // C0
    c[3] = fty * rfsy * Sy;                                    // A11
    c[4] = __builtin_fmaf(-fty * csy, rfsy, cty) * Sy;         // A12
    c[5] = (fty * t1 + cty * t2) * Sy;                         // C1
    c[6] = t2 + EPSF;                                          // t2e
    c[7] = 0.0f;
}

__global__ __launch_bounds__(256) void synth_view_kernel(
    const float* __restrict__ img, const float* __restrict__ disp,
    const float* __restrict__ cbuf, float* __restrict__ out)
{
    const int x = blockIdx.x * 256 + threadIdx.x;
    const int y = blockIdx.y;
    const int b = blockIdx.z;

    const float* cb = cbuf + b * 8;     // wave-uniform -> s_load
    const float A00 = cb[0], A02 = cb[1], C0 = cb[2];
    const float A11 = cb[3], A12 = cb[4], C1 = cb[5];
    const float t2e = cb[6];

    const int rowoff = y * WW + x;
    const float dsp = __builtin_nontemporal_load(disp + b * HW + rowoff);

    const float mind = 1.0f / 255.0f;
    const float rng  = 0.1f - mind;          // max_disp - min_disp
    const float sd   = __builtin_fmaf(dsp, rng, mind);
    const float r    = fast_rcp(__builtin_fmaf(t2e, sd, 1.0f));

    const float ax = __builtin_fmaf(A00, (float)x, A02);
    const float ay = __builtin_fmaf(A11, (float)y, A12);
    const float sx = __builtin_fmaf(__builtin_fmaf(C0, sd, ax), r, -0.5f);
    const float sy = __builtin_fmaf(__builtin_fmaf(C1, sd, ay), r, -0.5f);

    // Border-clamp bilinear, exactly, with NO index pairs / selects:
    //   ixc = clamp(floor(sx), 0, W-2); wx = clamp(sx - ixc, 0, 1)
    // interior: identical; clamped-low: wx=0 -> uses col ixc; clamped-high:
    // wx=1 -> uses col ixc+1 = W-1. Matches torch border semantics bit-exact.
    const int ix = (int)floorf(sx);
    const int iy = (int)floorf(sy);
    const int ixc = min(max(ix, 0), WW - 2);
    const int iyc = min(max(iy, 0), HH - 2);
    const float wx = fminf(fmaxf(sx - (float)ixc, 0.0f), 1.0f);
    const float wy = fminf(fmaxf(sy - (float)iyc, 0.0f), 1.0f);

    const int o0 = iyc * WW + ixc;   // top pair (cols ixc, ixc+1)
    const int o1 = o0 + WW;          // bottom pair

    const float wxm = 1.0f - wx, wym = 1.0f - wy;
    const float w00 = wxm * wym, w01 = wx * wym;
    const float w10 = wxm * wy,  w11 = wx * wy;

    const float* imb  = img + b * (3 * HW);
    float*       outb = out + b * (3 * HW) + rowoff;

#pragma unroll
    for (int c = 0; c < 3; ++c) {
        const float* ic = imb + c * HW;
        const f2u v0 = *reinterpret_cast<const f2u*>(ic + o0);  // i00,i01
        const f2u v1 = *reinterpret_cast<const f2u*>(ic + o1);  // i10,i11
        float acc =          v0.x * w00;
        acc = __builtin_fmaf(v0.y, w01, acc);
        acc = __builtin_fmaf(v1.x, w10, acc);
        acc = __builtin_fmaf(v1.y, w11, acc);
        __builtin_nontemporal_store(acc, outb + c * HW);
    }
}

extern "C" void kernel_launch(void* const* d_in, const int* in_sizes, int n_in,
                              void* d_out, int out_size, void* d_ws, size_t ws_size,
                              hipStream_t stream) {
    const float* img   = (const float*)d_in[0];
    const float* disp  = (const float*)d_in[1];
    const float* srcK  = (const float*)d_in[2];
    const float* tgtK  = (const float*)d_in[3];
    const float* trans = (const float*)d_in[4];
    float* out = (float*)d_out;
    float* cb  = (float*)d_ws;          // 8 batches x 8 floats = 256 B

    precompute_consts<<<dim3(1), dim3(64), 0, stream>>>(srcK, tgtK, trans, cb);

    dim3 block(256, 1, 1);
    dim3 grid(WW / 256, HH, BB);        // 5 x 1024 x 8 — 1 px/thread, full TLP
    synth_view_kernel<<<grid, block, 0, stream>>>(img, disp, cb, out);
}

// Round 4
// 254.376 us; speedup vs baseline: 1.0088x; 1.0088x over previous
//
#include <hip/hip_runtime.h>

#define BB 8
#define HH 1024
#define WW 1280
#define HW (HH * WW)
#define EPSF 1e-7f

__device__ __forceinline__ float fast_rcp(float x) {
    float r = __builtin_amdgcn_rcpf(x);
    r = r * __builtin_fmaf(-x, r, 2.0f);   // one NR step -> ~1 ulp
    return r;
}

// Per-batch constant folding: negligible cost. Writes 8 floats per batch.
__global__ void precompute_consts(
    const float* __restrict__ srcK, const float* __restrict__ tgtK,
    const float* __restrict__ trans, float* __restrict__ cb)
{
    const int b = threadIdx.x;
    if (b >= BB) return;
    const float* sK = srcK + b * 16;
    const float* tK = tgtK + b * 16;
    const float* tv = trans + b * 3;

    const float fsx = sK[0], csx = sK[2];
    const float fsy = sK[5], csy = sK[6];
    const float ftx = tK[0], ctx = tK[2];
    const float fty = tK[5], cty = tK[6];
    const float t0 = tv[0], t1 = tv[1], t2 = tv[2];

    // Closed form (K last row = [0,0,1], R = I):
    //   px = (A00*x + A02 + C0*sd) / (1 + (t2+eps)*sd),  sd = scaled_disp = 1/depth
    //   sx = px*W/(W-1) - 0.5   (grid unnormalize folded into A/C)
    const float Sx = (float)WW / (float)(WW - 1);
    const float Sy = (float)HH / (float)(HH - 1);
    const float rfsx = 1.0f / fsx;
    const float rfsy = 1.0f / fsy;
    float* c = cb + b * 8;
    c[0] = ftx * rfsx * Sx;                                    // A00
    c[1] = __builtin_fmaf(-ftx * csx, rfsx, ctx) * Sx;         // A02
    c[2] = (ftx * t0 + ctx * t2) * Sx;                         // C0
    c[3] = fty * rfsy * Sy;                                    // A11
    c[4] = __builtin_fmaf(-fty * csy, rfsy, cty) * Sy;         // A12
    c[5] = (fty * t1 + cty * t2) * Sy;                         // C1
    c[6] = t2 + EPSF;                                          // t2e
    c[7] = 0.0f;
}

__global__ __launch_bounds__(256) void synth_view_kernel(
    const float* __restrict__ img, const float* __restrict__ disp,
    const float* __restrict__ cbuf, float* __restrict__ out)
{
    const int x = blockIdx.x * 256 + threadIdx.x;
    const int b = blockIdx.z;

    const float* cb = cbuf + b * 8;     // wave-uniform -> scalar loads
    const float A00 = cb[0], A02 = cb[1], C0 = cb[2];
    const float A11 = cb[3], A12 = cb[4], C1 = cb[5];
    const float t2e = cb[6];

    // two independent pixels per thread: rows y and y+512
    const int yy[2] = { (int)blockIdx.y, (int)blockIdx.y + HH / 2 };
    const float* dbase = disp + b * HW;

    float dsp[2];
#pragma unroll
    for (int p = 0; p < 2; ++p)     // both loads issue before first use
        dsp[p] = __builtin_nontemporal_load(dbase + yy[p] * WW + x);

    const float mind = 1.0f / 255.0f;
    const float rng  = 0.1f - mind;          // max_disp - min_disp
    const float ax   = __builtin_fmaf(A00, (float)x, A02);   // row-invariant

    int   o0[2];
    float w00[2], w01[2], w10[2], w11[2];
#pragma unroll
    for (int p = 0; p < 2; ++p) {
        const float sd = __builtin_fmaf(dsp[p], rng, mind);
        const float r  = fast_rcp(__builtin_fmaf(t2e, sd, 1.0f));
        const float ay = __builtin_fmaf(A11, (float)yy[p], A12);
        const float sx = __builtin_fmaf(__builtin_fmaf(C0, sd, ax), r, -0.5f);
        const float sy = __builtin_fmaf(__builtin_fmaf(C1, sd, ay), r, -0.5f);

        // Border-clamp bilinear via weight folding (exact, no selects):
        //   ixc = clamp(floor(sx), 0, W-2); wx = clamp(sx - ixc, 0, 1)
        const int ix = (int)floorf(sx);
        const int iy = (int)floorf(sy);
        const int ixc = min(max(ix, 0), WW - 2);
        const int iyc = min(max(iy, 0), HH - 2);
        const float wx = fminf(fmaxf(sx - (float)ixc, 0.0f), 1.0f);
        const float wy = fminf(fmaxf(sy - (float)iyc, 0.0f), 1.0f);

        o0[p] = iyc * WW + ixc;
        const float wxm = 1.0f - wx, wym = 1.0f - wy;
        w00[p] = wxm * wym; w01[p] = wx * wym;
        w10[p] = wxm * wy;  w11[p] = wx * wy;
    }

    const float* imb  = img + b * (3 * HW);
    float*       outb = out + b * (3 * HW);

#pragma unroll
    for (int c = 0; c < 3; ++c) {
        const float* ic = imb + c * HW;
#pragma unroll
        for (int p = 0; p < 2; ++p) {        // 8 independent dword gathers/channel
            const int o = o0[p];
            float acc =          ic[o]          * w00[p];
            acc = __builtin_fmaf(ic[o + 1],      w01[p], acc);
            acc = __builtin_fmaf(ic[o + WW],     w10[p], acc);
            acc = __builtin_fmaf(ic[o + WW + 1], w11[p], acc);
            __builtin_nontemporal_store(acc, outb + c * HW + yy[p] * WW + x);
        }
    }
}

extern "C" void kernel_launch(void* const* d_in, const int* in_sizes, int n_in,
                              void* d_out, int out_size, void* d_ws, size_t ws_size,
                              hipStream_t stream) {
    const float* img   = (const float*)d_in[0];
    const float* disp  = (const float*)d_in[1];
    const float* srcK  = (const float*)d_in[2];
    const float* tgtK  = (const float*)d_in[3];
    const float* trans = (const float*)d_in[4];
    float* out = (float*)d_out;
    float* cb  = (float*)d_ws;          // 8 batches x 8 floats = 256 B

    precompute_consts<<<dim3(1), dim3(64), 0, stream>>>(srcK, tgtK, trans, cb);

    dim3 block(256, 1, 1);
    dim3 grid(WW / 256, HH / 2, BB);    // 5 x 512 x 8 — 2 px/thread (rows y, y+512)
    synth_view_kernel<<<grid, block, 0, stream>>>(img, disp, cb, out);
}